// Round 9
// baseline (1760.682 us; speedup 1.0000x reference)
//
#include <hip/hip_runtime.h>

#define BB 64
#define TT 2048
#define INW 64
#define HH 256
#define NXB 512                  // xprep blocks
#define RPB ((BB * TT) / NXB)    // 256 rows per xprep block
#define NW 8                     // scan waves
#define KC (HH / NW)             // 32: k-chunk per wave
#define PSTR 260                 // part[] row stride (floats)

typedef float v2f __attribute__((ext_vector_type(2)));

__device__ __forceinline__ v2f fma2(v2f a, v2f b, v2f c) {
#if __has_builtin(__builtin_elementwise_fma)
    return __builtin_elementwise_fma(a, b, c);   // -> v_pk_fma_f32
#else
    v2f r; r.x = __builtin_fmaf(a.x, b.x, c.x); r.y = __builtin_fmaf(a.y, b.y, c.y); return r;
#endif
}

__device__ __forceinline__ float fast_tanh(float x) {
    // tanh(x) = 1 - 2/(e^{2x}+1); saturates correctly at +/-inf
    float e = __expf(2.0f * x);
    return 1.0f - 2.0f / (e + 1.0f);
}

// LDS-only barrier: skip the vmcnt(0) drain __syncthreads() would add, so
// u-store acks / X prefetches stay off the per-step critical path.
__device__ __forceinline__ void lds_barrier() {
    asm volatile("s_waitcnt lgkmcnt(0)" ::: "memory");
    __builtin_amdgcn_s_barrier();
    __builtin_amdgcn_sched_barrier(0);
}

// ---------------------------------------------------------------------------
// Pre-pass: X[row,h] = I[row,:] . W_in[h,:] + b[h]  (no recurrence dependence).
// ---------------------------------------------------------------------------
__global__ __launch_bounds__(256)
void xprep(const float* __restrict__ I,
           const float* __restrict__ W_in,
           const float* __restrict__ bias,
           float* __restrict__ X)
{
    const int h = threadIdx.x;
    const size_t row0 = (size_t)blockIdx.x * RPB;

    v2f w[32];
    {
        const float4* wp = (const float4*)(W_in + (size_t)h * INW);
        #pragma unroll
        for (int i = 0; i < 16; ++i) {
            float4 a = wp[i];
            w[2*i]     = (v2f){a.x, a.y};
            w[2*i + 1] = (v2f){a.z, a.w};
        }
    }
    const float bv = bias[h];

    for (int r = 0; r < RPB; ++r) {
        const float4* ip = (const float4*)(I + (row0 + r) * INW);
        v2f acc0 = {0.f, 0.f}, acc1 = {0.f, 0.f};
        #pragma unroll
        for (int i = 0; i < 16; ++i) {
            float4 iv = ip[i];
            acc0 = fma2(w[2*i],     (v2f){iv.x, iv.y}, acc0);
            acc1 = fma2(w[2*i + 1], (v2f){iv.z, iv.w}, acc1);
        }
        v2f s = acc0 + acc1;
        X[(row0 + r) * HH + h] = s.x + s.y + bv;
    }
}

// ---------------------------------------------------------------------------
// Serial scan. One workgroup per batch, 512 threads (8 waves).
//
// LDS-throughput-minimal decomposition (profiling showed step time tracks
// weighted LDS-instruction count across 5 structural variants, not VALU or
// register placement): wave w owns k in [32w, 32w+32); lane l owns h-rows
// [4l, 4l+4) -- every wave covers ALL 256 h for a DISJOINT k-chunk, so the
// r-vector is broadcast-read exactly once per wave: 8 uniform ds_read_b128
// per wave, 64 per CU per step (the family floor; R5 did 128 + extras).
// Weights: 4 rows x 32 k = 128 f32/lane, loop-invariant.
// Per step: 8 b128 r-reads -> 64 pk_fma -> ONE b128 partial write
// part[w][4l..4l+4) -> barrier -> 256 threads combine 8 partials (b32,
// conflict-free) + X, update u, store u, write r_buf; wave 4 stages X ->
// barrier. Reduction tree order identical to R5 (same k-partition, same
// within-chunk chains) -> bitwise-stable absmax.
// ---------------------------------------------------------------------------
__global__ __launch_bounds__(512, 1)
void rnn_scan(const float* __restrict__ x0,
              const float* __restrict__ W_rec,
              float* uX)                      // aliased: X (read) / u_out (write)
{
    __shared__ __align__(16) float r_buf[HH];
    __shared__ __align__(16) float xbuf[2][HH];
    __shared__ __align__(16) float part[NW][PSTR];

    const int b    = blockIdx.x;
    const int tid  = threadIdx.x;
    const int lane = tid & 63;
    const int w    = tid >> 6;         // wave id, 0..7
    const int k0   = w * KC;
    const int h0   = lane * 4;         // this lane's 4 output rows
    const int il   = tid - 256;        // wave 4 lanes stage X rows

    // ---- loop-invariant W_rec tile: rows h0..h0+3, cols k0..k0+31 ----
    v2f wr[4][16];
    #pragma unroll
    for (int m = 0; m < 4; ++m) {
        const float4* wp = (const float4*)(W_rec + (size_t)(h0 + m) * HH + k0);
        #pragma unroll
        for (int i = 0; i < 8; ++i) {
            float4 a = wp[i];
            wr[m][2*i]     = (v2f){a.x, a.y};
            wr[m][2*i + 1] = (v2f){a.z, a.w};
        }
    }

    // ---- state init (u owned by tid<256) ----
    float u = 0.0f;
    if (tid < HH) {
        u = x0[(size_t)b * HH + tid];
        r_buf[tid] = fast_tanh(u);
    }
    if (tid < 64)   // stage X[b,0]
        ((float4*)&xbuf[0][0])[tid] = ((const float4*)(uX + (size_t)b * TT * HH))[tid];
    float4 x_next = {0.f, 0.f, 0.f, 0.f};
    if ((unsigned)il < 64u)  // wave 4: X[b,1] in flight
        x_next = ((const float4*)(uX + ((size_t)b * TT + 1) * HH))[il];
    __syncthreads();

    const float4* rb4 = (const float4*)&r_buf[k0];

    for (int t = 0; t < TT; ++t) {
        // wave 4: issue X[b,t+2] (consumed end of step t+1; ~2 steps of cover)
        float4 x_fut = {0.f, 0.f, 0.f, 0.f};
        if ((unsigned)il < 64u && (t + 2) < TT)
            x_fut = ((const float4*)(uX + ((size_t)b * TT + t + 2) * HH))[il];

        // ---- partial dots: 4 rows x k-chunk w (8 uniform b128 broadcasts) ----
        v2f a0[4] = {{0.f,0.f},{0.f,0.f},{0.f,0.f},{0.f,0.f}};
        v2f a1[4] = {{0.f,0.f},{0.f,0.f},{0.f,0.f},{0.f,0.f}};
        #pragma unroll
        for (int i = 0; i < 8; ++i) {
            float4 r4 = rb4[i];                      // wave-uniform -> broadcast
            v2f r01 = (v2f){r4.x, r4.y}, r23 = (v2f){r4.z, r4.w};
            #pragma unroll
            for (int m = 0; m < 4; ++m) {
                a0[m] = fma2(wr[m][2*i],     r01, a0[m]);
                a1[m] = fma2(wr[m][2*i + 1], r23, a1[m]);
            }
        }
        float4 dv;
        { v2f s = a0[0] + a1[0]; dv.x = s.x + s.y; }
        { v2f s = a0[1] + a1[1]; dv.y = s.x + s.y; }
        { v2f s = a0[2] + a1[2]; dv.z = s.x + s.y; }
        { v2f s = a0[3] + a1[3]; dv.w = s.x + s.y; }
        *(float4*)&part[w][h0] = dv;                 // one b128 write per lane
        lds_barrier();                               // partials visible; r reads done

        if (tid < HH) {
            float d = (((part[0][tid] + part[1][tid]) + (part[2][tid] + part[3][tid])) +
                       ((part[4][tid] + part[5][tid]) + (part[6][tid] + part[7][tid])))
                      + xbuf[t & 1][tid];
            u = 0.8f * u + 0.2f * d;
            uX[((size_t)b * TT + t) * HH + tid] = u;
            r_buf[tid] = fast_tanh(u);
        }
        if ((unsigned)il < 64u && (t + 1) < TT)      // wave 4 publishes X[b,t+1]
            *(float4*)&xbuf[(t + 1) & 1][4 * il] = x_next;
        x_next = x_fut;
        lds_barrier();                               // new r / xbuf visible for t+1
    }
}

// y[b,t,o] = sum_h u[b,t,h] * Wout[o,h] + bout[o]. One wave per (b,t) row.
__global__ __launch_bounds__(256)
void readout(const float* __restrict__ u,
             const float* __restrict__ Wout,
             const float* __restrict__ bout,
             float* __restrict__ y)
{
    const int wid  = threadIdx.x >> 6;
    const int lane = threadIdx.x & 63;
    const size_t row = (size_t)blockIdx.x * 4 + wid;   // < BB*TT

    float4 uv = ((const float4*)(u + row * HH))[lane];
    float4 w0 = ((const float4*)Wout)[lane];
    float4 w1 = ((const float4*)(Wout + HH))[lane];

    float acc0 = uv.x * w0.x + uv.y * w0.y + uv.z * w0.z + uv.w * w0.w;
    float acc1 = uv.x * w1.x + uv.y * w1.y + uv.z * w1.z + uv.w * w1.w;

    #pragma unroll
    for (int m = 32; m >= 1; m >>= 1) {
        acc0 += __shfl_xor(acc0, m, 64);
        acc1 += __shfl_xor(acc1, m, 64);
    }
    if (lane == 0) {
        y[row * 2 + 0] = acc0 + bout[0];
        y[row * 2 + 1] = acc1 + bout[1];
    }
}

extern "C" void kernel_launch(void* const* d_in, const int* in_sizes, int n_in,
                              void* d_out, int out_size, void* d_ws, size_t ws_size,
                              hipStream_t stream) {
    const float* x0    = (const float*)d_in[0];
    const float* I     = (const float*)d_in[1];
    const float* W_in  = (const float*)d_in[2];
    const float* W_rec = (const float*)d_in[3];
    const float* bias  = (const float*)d_in[4];
    const float* Wout  = (const float*)d_in[5];
    const float* bout  = (const float*)d_in[6];

    float* u_out = (float*)d_out;                       // also holds X pre-scan
    float* y_out = u_out + (size_t)BB * TT * HH;

    xprep<<<NXB, 256, 0, stream>>>(I, W_in, bias, u_out);
    rnn_scan<<<BB, 512, 0, stream>>>(x0, W_rec, u_out);
    readout<<<(BB * TT) / 4, 256, 0, stream>>>(u_out, Wout, bout, y_out);
}